// Round 15
// baseline (1567.485 us; speedup 1.0000x reference)
//
#include <hip/hip_runtime.h>
#include <hip/hip_bf16.h>
#include <math.h>

#define N_NODES 100000
#define N_EDGES 1200000
#define N_GRAPHS 512
#define NBUCKET 196          // ceil(N_NODES / 512)
#define BSHIFT 9             // bucket = dst >> 9 (512 nodes/bucket)
#define TILE 2048            // edges per partition tile
#define CSR_CAP 8192         // LDS staging capacity in bucket_csr (mean 6122, sd ~78)

typedef __bf16 bf16x8 __attribute__((ext_vector_type(8)));
typedef float f32x4 __attribute__((ext_vector_type(4)));

// ---- float <-> monotonic unsigned (for atomicMax on floats) ----
__device__ __forceinline__ unsigned f2ord(float f) {
  unsigned u = __float_as_uint(f);
  return (u & 0x80000000u) ? ~u : (u | 0x80000000u);
}
__device__ __forceinline__ float ord2f(unsigned u) {
  return (u & 0x80000000u) ? __uint_as_float(u & 0x7fffffffu) : __uint_as_float(~u);
}

// ---------------- two-level counting-sort CSR build -------------------------
__global__ void bucket_hist_kernel(const int* __restrict__ dst, int* __restrict__ bcnt) {
  __shared__ int c[256];
  int t = threadIdx.x;
  c[t] = 0;
  __syncthreads();
  for (int e = blockIdx.x * 256 + t; e < N_EDGES; e += gridDim.x * 256)
    atomicAdd(&c[dst[e] >> BSHIFT], 1);
  __syncthreads();
  if (t < NBUCKET && c[t] > 0) atomicAdd(&bcnt[t], c[t]);
}

__global__ void bucket_scan_kernel(const int* __restrict__ bcnt,
                                   int* __restrict__ bbase,
                                   int* __restrict__ bcursor,
                                   int* __restrict__ rowp) {
  __shared__ int s[256];
  int t = threadIdx.x;
  int own = (t < NBUCKET) ? bcnt[t] : 0;
  s[t] = own;
  __syncthreads();
  for (int o = 1; o < 256; o <<= 1) {
    int v = (t >= o) ? s[t - o] : 0;
    __syncthreads();
    s[t] += v;
    __syncthreads();
  }
  if (t < NBUCKET) {
    int excl = s[t] - own;
    bbase[t] = excl;
    bcursor[t] = excl;
  }
  if (t == 0) {
    bbase[NBUCKET] = N_EDGES;
    rowp[N_NODES] = N_EDGES;
  }
}

// entry = src | (dst & 511) << 17   (src < 2^17, dst_local < 512)
__global__ void partition_kernel(const int* __restrict__ src, const int* __restrict__ dst,
                                 int* __restrict__ bcursor, unsigned* __restrict__ ent) {
  __shared__ int cnt[256];
  __shared__ int cnt2[256];
  __shared__ int lstart[256];
  __shared__ int gbase[256];
  __shared__ int s[256];
  __shared__ unsigned sorted[TILE];
  __shared__ unsigned char bid[TILE];
  int t = threadIdx.x;
  int e0 = blockIdx.x * TILE;
  cnt[t] = 0; cnt2[t] = 0;
  __syncthreads();

  unsigned v[8];
  int b[8];
#pragma unroll
  for (int u = 0; u < 8; ++u) {
    int e = e0 + u * 256 + t;
    b[u] = -1;
    if (e < N_EDGES) {
      int d = dst[e];
      b[u] = d >> BSHIFT;
      v[u] = (unsigned)src[e] | ((unsigned)(d & 511) << 17);
      atomicAdd(&cnt[b[u]], 1);
    }
  }
  __syncthreads();
  s[t] = cnt[t];
  __syncthreads();
  for (int o = 1; o < 256; o <<= 1) {
    int x = (t >= o) ? s[t - o] : 0;
    __syncthreads();
    s[t] += x;
    __syncthreads();
  }
  lstart[t] = s[t] - cnt[t];
  __syncthreads();
  if (t < NBUCKET) gbase[t] = (cnt[t] > 0) ? atomicAdd(&bcursor[t], cnt[t]) : 0;
  __syncthreads();
#pragma unroll
  for (int u = 0; u < 8; ++u) {
    if (b[u] >= 0) {
      int p = lstart[b[u]] + atomicAdd(&cnt2[b[u]], 1);
      sorted[p] = v[u];
      bid[p] = (unsigned char)b[u];
    }
  }
  __syncthreads();
  int ntile = min(TILE, N_EDGES - e0);
  for (int i = t; i < ntile; i += 256) {
    int bb = bid[i];
    ent[gbase[bb] + (i - lstart[bb])] = sorted[i];
  }
}

// K4: per-bucket fine CSR. Output entry packs src + 64-block-local row:
//   epack[p] = src | ((node_in_bucket & 63) << 17)
__launch_bounds__(256)
__global__ void bucket_csr_kernel(const unsigned* __restrict__ ent,
                                  const int* __restrict__ bbase,
                                  int* __restrict__ rowp,
                                  unsigned* __restrict__ epack) {
  __shared__ unsigned le[CSR_CAP];   // 32 KB
  __shared__ int deg[512];           // reused as scatter cursor
  __shared__ int excl[512];
  __shared__ int ws[256];
  int t = threadIdx.x;
  int b = blockIdx.x;
  int base = bbase[b];
  int cntb = bbase[b + 1] - base;
  deg[t] = 0; deg[t + 256] = 0;
  __syncthreads();
  for (int i = t; i < cntb; i += 256) {
    unsigned e = ent[base + i];
    if (i < CSR_CAP) le[i] = e;
    atomicAdd(&deg[e >> 17], 1);
  }
  __syncthreads();
  int d0 = deg[t * 2], d1 = deg[t * 2 + 1];
  int sum2 = d0 + d1;
  ws[t] = sum2;
  __syncthreads();
  for (int o = 1; o < 256; o <<= 1) {
    int x = (t >= o) ? ws[t - o] : 0;
    __syncthreads();
    ws[t] += x;
    __syncthreads();
  }
  int run = ws[t] - sum2;
  excl[t * 2] = run; run += d0;
  excl[t * 2 + 1] = run;
  __syncthreads();
  int node0 = b << BSHIFT;
#pragma unroll
  for (int k = 0; k < 2; ++k) {
    int i = t * 2 + k;
    int n = node0 + i;
    if (n < N_NODES) rowp[n] = base + excl[i];
    deg[i] = excl[i];
  }
  __syncthreads();
  for (int i = t; i < cntb; i += 256) {
    unsigned e = (i < CSR_CAP) ? le[i] : ent[base + i];
    int p = atomicAdd(&deg[e >> 17], 1);
    epack[base + p] = (e & 0x1FFFFu) | (((e >> 17) & 63u) << 17);
  }
}

// ---------------- dense pipeline ---------------------------------------------
// h0 = x @ W_emb + b_emb   (x: [N,7], W: [7,64]) -> bf16
__global__ void embed_kernel(const float* __restrict__ x,
                             const float* __restrict__ W,
                             const float* __restrict__ b,
                             __bf16* __restrict__ h) {
  __shared__ float Ws[7 * 64];
  __shared__ float bs[64];
  int t = threadIdx.x;
  for (int i = t; i < 7 * 64; i += 256) Ws[i] = W[i];
  if (t < 64) bs[t] = b[t];
  __syncthreads();
  int gid = blockIdx.x * 256 + t;
  int n = gid >> 6, f = gid & 63;
  const float* xr = x + n * 7;
  float acc = bs[f];
#pragma unroll
  for (int k = 0; k < 7; ++k) acc = fmaf(xr[k], Ws[k * 64 + f], acc);
  h[gid] = (__bf16)acc;
}

// Pre-permute all 3 layers' weights into bf16 MFMA B-fragment order;
// also folds the pool-accumulator init.
__global__ void convert_all_kernel(const float* __restrict__ W1a, const float* __restrict__ W1b,
                                   const float* __restrict__ W2a, const float* __restrict__ W2b,
                                   const float* __restrict__ W3a, const float* __restrict__ W3b,
                                   __bf16* __restrict__ wp,
                                   float* gsum, unsigned* gmax, int* gcnt) {
  int o = blockIdx.x * 256 + threadIdx.x;  // 0..49151
  if (o < N_GRAPHS * 64) {
    gsum[o] = 0.0f;
    gmax[o] = 0x407FFFFFu;  // f2ord(-1.0f); elu outputs > -1, safe identity
  }
  if (o < N_GRAPHS) gcnt[o] = 0;
  int L = o >> 14, q = o & 16383;
  const float* Wa = (L == 0) ? W1a : (L == 1) ? W2a : W3a;
  const float* Wb = (L == 0) ? W1b : (L == 1) ? W2b : W3b;
  if (q < 8192) {
    int j = q & 7, c = (q >> 3) & 15, kc = (q >> 7) & 3, kt = (q >> 9) & 1, nt = q >> 10;
    wp[o] = (__bf16)Wa[(kt * 32 + kc * 8 + j) * 128 + nt * 16 + c];
  } else {
    int p = q - 8192;
    int j = p & 7, c = (p >> 3) & 15, kc = (p >> 7) & 3, kt = (p >> 9) & 3, nt2 = p >> 11;
    wp[o] = (__bf16)Wb[(kt * 32 + kc * 8 + j) * 64 + nt2 * 16 + c];
  }
}

// Fused GIN layer, batch-issue gather + LDS f32 atomic accumulate:
// per wave: contiguous edge range [rowp[n0w], rowp[n0w+16]); chunks of 16
// packed entries (scalar loads) -> 16 gather loads in flight -> 16 ds_add_f32.
// No __shfl in the chain (r4's serializer); rows wave-private -> no barriers.
__launch_bounds__(256)
__global__ void gin_fused6_kernel(const __bf16* __restrict__ hin,
                                  __bf16* __restrict__ hout,
                                  const int* __restrict__ row_ptr,
                                  const unsigned* __restrict__ epack,
                                  const float* __restrict__ eps_p,
                                  const __bf16* __restrict__ W1p,
                                  const float* __restrict__ b1,
                                  const __bf16* __restrict__ W2p,
                                  const float* __restrict__ b2) {
  __shared__ float Ag[64 * 68];       // 17408 B; reused as Hs bf16[64][136]
  __bf16* Hs = (__bf16*)Ag;
  int t = threadIdx.x, lane = t & 63, wv = t >> 6;
  int c = lane & 15, kc = lane >> 4;
  int m0 = wv * 16;
  float epsv = 1.0f + eps_p[0];
  int n0b = blockIdx.x * 64;
  int n0w = n0b + m0;

  // self-term init (wave-private rows)
#pragma unroll
  for (int r = 0; r < 16; ++r) {
    int n = n0w + r;
    float v = (n < N_NODES) ? epsv * (float)hin[(size_t)n * 64 + lane] : 0.0f;
    Ag[(m0 + r) * 68 + lane] = v;
  }

  int rs = __builtin_amdgcn_readfirstlane(row_ptr[min(n0w, N_NODES)]);
  int re = __builtin_amdgcn_readfirstlane(row_ptr[min(n0w + 16, N_NODES)]);

  int k = rs;
  while (k + 16 <= re) {
    unsigned ev[16];
#pragma unroll
    for (int i = 0; i < 16; ++i) ev[i] = epack[k + i];
    float fv[16];
#pragma unroll
    for (int i = 0; i < 16; ++i)
      fv[i] = (float)hin[(size_t)(ev[i] & 0x1FFFFu) * 64 + lane];
#pragma unroll
    for (int i = 0; i < 16; ++i)
      atomicAdd(&Ag[(ev[i] >> 17) * 68 + lane], fv[i]);
    k += 16;
  }
  while (k + 4 <= re) {
    unsigned ev[4];
#pragma unroll
    for (int i = 0; i < 4; ++i) ev[i] = epack[k + i];
    float fv[4];
#pragma unroll
    for (int i = 0; i < 4; ++i)
      fv[i] = (float)hin[(size_t)(ev[i] & 0x1FFFFu) * 64 + lane];
#pragma unroll
    for (int i = 0; i < 4; ++i)
      atomicAdd(&Ag[(ev[i] >> 17) * 68 + lane], fv[i]);
    k += 4;
  }
  for (; k < re; ++k) {
    unsigned e = epack[k];
    float f = (float)hin[(size_t)(e & 0x1FFFFu) * 64 + lane];
    atomicAdd(&Ag[(e >> 17) * 68 + lane], f);
  }

  // fragments from f32 Ag (per-wave in-order DS: adds retire before reads)
  bf16x8 a1_0, a1_1;
  {
    const float* rowa = &Ag[(m0 + c) * 68];
#pragma unroll
    for (int i = 0; i < 8; ++i) {
      a1_0[i] = (__bf16)rowa[kc * 8 + i];
      a1_1[i] = (__bf16)rowa[32 + kc * 8 + i];
    }
  }

  // GEMM1: [16x64] @ [64x128]
  f32x4 acc1[8];
#pragma unroll
  for (int nt = 0; nt < 8; ++nt) {
    float bv = b1[nt * 16 + c];
    f32x4 acc = {bv, bv, bv, bv};
    bf16x8 bf0 = *(const bf16x8*)&W1p[(nt * 2 + 0) * 512 + kc * 128 + c * 8];
    bf16x8 bf1 = *(const bf16x8*)&W1p[(nt * 2 + 1) * 512 + kc * 128 + c * 8];
    acc = __builtin_amdgcn_mfma_f32_16x16x32_bf16(a1_0, bf0, acc, 0, 0, 0);
    acc = __builtin_amdgcn_mfma_f32_16x16x32_bf16(a1_1, bf1, acc, 0, 0, 0);
    acc1[nt] = acc;
  }
  // relu -> bf16 hidden tile overwriting the slab (per-wave in-order DS:
  // the fragment reads above complete before these writes)
#pragma unroll
  for (int nt = 0; nt < 8; ++nt) {
#pragma unroll
    for (int r = 0; r < 4; ++r) {
      Hs[(m0 + kc * 4 + r) * 136 + nt * 16 + c] = (__bf16)fmaxf(acc1[nt][r], 0.0f);
    }
  }

  // GEMM2: [16x128] @ [128x64]
  bf16x8 a2[4];
#pragma unroll
  for (int kt = 0; kt < 4; ++kt)
    a2[kt] = *(const bf16x8*)&Hs[(m0 + c) * 136 + kt * 32 + kc * 8];
#pragma unroll
  for (int nt2 = 0; nt2 < 4; ++nt2) {
    float bv = b2[nt2 * 16 + c];
    f32x4 acc = {bv, bv, bv, bv};
#pragma unroll
    for (int kt = 0; kt < 4; ++kt) {
      bf16x8 bf = *(const bf16x8*)&W2p[(nt2 * 4 + kt) * 512 + kc * 128 + c * 8];
      acc = __builtin_amdgcn_mfma_f32_16x16x32_bf16(a2[kt], bf, acc, 0, 0, 0);
    }
#pragma unroll
    for (int r = 0; r < 4; ++r) {
      int g = n0b + m0 + kc * 4 + r;
      if (g < N_NODES) {
        float o = acc[r];
        hout[(size_t)g * 64 + nt2 * 16 + c] = (__bf16)((o > 0.0f) ? o : expm1f(o));
      }
    }
  }
}

// per-graph sum/max/count; batch sorted -> wave scans contiguous chunk
__global__ void pool_kernel(const __bf16* __restrict__ h,
                            const int* __restrict__ batch,
                            float* gsum, unsigned* gmax, int* gcnt) {
  int lane = threadIdx.x & 63;
  int wave = (blockIdx.x * blockDim.x + threadIdx.x) >> 6;
  int nwaves = (gridDim.x * blockDim.x) >> 6;
  int chunk = (N_NODES + nwaves - 1) / nwaves;
  int n0 = wave * chunk;
  int n1 = min(n0 + chunk, N_NODES);
  if (n0 >= N_NODES) return;
  int cur = batch[n0];
  float s = 0.0f, m = -2.0f;
  int cnt = 0;
  for (int n = n0; n < n1; ++n) {
    int g = batch[n];
    if (g != cur) {
      atomicAdd(&gsum[cur * 64 + lane], s);
      atomicMax(&gmax[cur * 64 + lane], f2ord(m));
      if (lane == 0) atomicAdd(&gcnt[cur], cnt);
      cur = g; s = 0.0f; m = -2.0f; cnt = 0;
    }
    float v = (float)h[(size_t)n * 64 + lane];
    s += v;
    m = fmaxf(m, v);
    ++cnt;
  }
  atomicAdd(&gsum[cur * 64 + lane], s);
  atomicMax(&gmax[cur * 64 + lane], f2ord(m));
  if (lane == 0) atomicAdd(&gcnt[cur], cnt);
}

// out = relu([mean|max] @ Wc1 + bc1) @ Wc2 + bc2 ; one 64-thread block / graph
__global__ void cls_kernel(const float* __restrict__ gsum,
                           const unsigned* __restrict__ gmax,
                           const int* __restrict__ gcnt,
                           const float* __restrict__ Wc1,
                           const float* __restrict__ bc1,
                           const float* __restrict__ Wc2,
                           const float* __restrict__ bc2,
                           float* __restrict__ out) {
  __shared__ float gv[128];
  __shared__ float tv[64];
  int g = blockIdx.x, l = threadIdx.x;
  float cnt = fmaxf((float)gcnt[g], 1.0f);
  gv[l] = gsum[g * 64 + l] / cnt;
  gv[64 + l] = ord2f(gmax[g * 64 + l]);
  __syncthreads();
  float acc = bc1[l];
#pragma unroll 8
  for (int k = 0; k < 128; ++k) acc = fmaf(gv[k], Wc1[k * 64 + l], acc);
  tv[l] = fmaxf(acc, 0.0f);
  __syncthreads();
  if (l < 10) {
    float o = bc2[l];
#pragma unroll
    for (int k = 0; k < 64; ++k) o = fmaf(tv[k], Wc2[k * 10 + l], o);
    out[g * 10 + l] = o;
  }
}

extern "C" void kernel_launch(void* const* d_in, const int* in_sizes, int n_in,
                              void* d_out, int out_size, void* d_ws, size_t ws_size,
                              hipStream_t stream) {
  const float* x     = (const float*)d_in[0];
  const int*   ei    = (const int*)d_in[1];
  const int*   batch = (const int*)d_in[2];
  const float* W_emb = (const float*)d_in[3];
  const float* b_emb = (const float*)d_in[4];
  const float* eps1  = (const float*)d_in[5];
  const float* W1a   = (const float*)d_in[6];
  const float* b1a   = (const float*)d_in[7];
  const float* W1b   = (const float*)d_in[8];
  const float* b1b   = (const float*)d_in[9];
  const float* eps2  = (const float*)d_in[10];
  const float* W2a   = (const float*)d_in[11];
  const float* b2a   = (const float*)d_in[12];
  const float* W2b   = (const float*)d_in[13];
  const float* b2b   = (const float*)d_in[14];
  const float* eps3  = (const float*)d_in[15];
  const float* W3a   = (const float*)d_in[16];
  const float* b3a   = (const float*)d_in[17];
  const float* W3b   = (const float*)d_in[18];
  const float* b3b   = (const float*)d_in[19];
  const float* Wc1   = (const float*)d_in[20];
  const float* bc1   = (const float*)d_in[21];
  const float* Wc2   = (const float*)d_in[22];
  const float* bc2   = (const float*)d_in[23];
  float* out = (float*)d_out;

  // workspace layout (byte-based)
  char* w = (char*)d_ws;
  __bf16*   h0   = (__bf16*)w;                     w += (size_t)N_NODES * 64 * 2;  // 12.8MB
  __bf16*   h1   = (__bf16*)w;                     w += (size_t)N_NODES * 64 * 2;  // 12.8MB
  float*    gsum = (float*)w;                      w += N_GRAPHS * 64 * 4;
  unsigned* gmax = (unsigned*)w;                   w += N_GRAPHS * 64 * 4;
  int*      gcnt = (int*)w;                        w += N_GRAPHS * 4;
  __bf16*   wp   = (__bf16*)w;                     w += 3 * 16384 * 2;
  int*      bcnt = (int*)w;                        w += 256 * 4;
  int*      bbase= (int*)w;                        w += 260 * 4;
  int*      bcur = (int*)w;                        w += 256 * 4;
  int*      rowp = (int*)w;                        w += (size_t)(N_NODES + 1) * 4;
  unsigned* ent  = (unsigned*)w;                   w += (size_t)N_EDGES * 4;      // 4.8MB
  unsigned* epk  = (unsigned*)w;                   w += (size_t)N_EDGES * 4;      // 4.8MB

  const int* src = ei;             // edge_index[0]
  const int* dst = ei + N_EDGES;   // edge_index[1]

  const float* epss[3] = {eps1, eps2, eps3};
  const float* bas[3]  = {b1a, b2a, b3a};
  const float* bbs[3]  = {b1b, b2b, b3b};

  // ---- CSR build via two-level counting sort (edge list shared by layers) --
  hipMemsetAsync(bcnt, 0, 256 * sizeof(int), stream);
  bucket_hist_kernel<<<256, 256, 0, stream>>>(dst, bcnt);
  bucket_scan_kernel<<<1, 256, 0, stream>>>(bcnt, bbase, bcur, rowp);
  partition_kernel<<<(N_EDGES + TILE - 1) / TILE, 256, 0, stream>>>(src, dst, bcur, ent);
  bucket_csr_kernel<<<NBUCKET, 256, 0, stream>>>(ent, bbase, rowp, epk);

  convert_all_kernel<<<192, 256, 0, stream>>>(W1a, W1b, W2a, W2b, W3a, W3b, wp,
                                              gsum, gmax, gcnt);
  embed_kernel<<<(N_NODES * 64) / 256, 256, 0, stream>>>(x, W_emb, b_emb, h0);

  const int NGB = (N_NODES + 63) / 64;
  __bf16* hbuf[4] = {h0, h1, h0, h1};
  for (int L = 0; L < 3; ++L) {
    gin_fused6_kernel<<<NGB, 256, 0, stream>>>(
        hbuf[L], hbuf[L + 1], rowp, epk, epss[L],
        wp + (size_t)L * 16384, bas[L],
        wp + (size_t)L * 16384 + 8192, bbs[L]);
  }

  pool_kernel<<<512, 256, 0, stream>>>(h1, batch, gsum, gmax, gcnt);
  cls_kernel<<<N_GRAPHS, 64, 0, stream>>>(gsum, gmax, gcnt, Wc1, bc1, Wc2, bc2, out);
}

// Round 17
// 398.505 us; speedup vs baseline: 3.9334x; 3.9334x over previous
//
#include <hip/hip_runtime.h>
#include <hip/hip_bf16.h>
#include <math.h>

#define N_NODES 100000
#define N_EDGES 1200000
#define N_GRAPHS 512
#define NBUCKET 196          // ceil(N_NODES / 512)
#define BSHIFT 9             // bucket = dst >> 9 (512 nodes/bucket)
#define TILE 2048            // edges per partition tile
#define CSR_CAP 8192         // LDS staging capacity in bucket_csr (mean 6122, sd ~78)

typedef __bf16 bf16x8 __attribute__((ext_vector_type(8)));
typedef float f32x4 __attribute__((ext_vector_type(4)));

// ---- float <-> monotonic unsigned (for atomicMax on floats) ----
__device__ __forceinline__ unsigned f2ord(float f) {
  unsigned u = __float_as_uint(f);
  return (u & 0x80000000u) ? ~u : (u | 0x80000000u);
}
__device__ __forceinline__ float ord2f(unsigned u) {
  return (u & 0x80000000u) ? __uint_as_float(u & 0x7fffffffu) : __uint_as_float(~u);
}

// ---------------- two-level counting-sort CSR build (r6, proven) ------------
__global__ void bucket_hist_kernel(const int* __restrict__ dst, int* __restrict__ bcnt) {
  __shared__ int c[256];
  int t = threadIdx.x;
  c[t] = 0;
  __syncthreads();
  for (int e = blockIdx.x * 256 + t; e < N_EDGES; e += gridDim.x * 256)
    atomicAdd(&c[dst[e] >> BSHIFT], 1);
  __syncthreads();
  if (t < NBUCKET && c[t] > 0) atomicAdd(&bcnt[t], c[t]);
}

__global__ void bucket_scan_kernel(const int* __restrict__ bcnt,
                                   int* __restrict__ bbase,
                                   int* __restrict__ bcursor,
                                   int* __restrict__ rowp) {
  __shared__ int s[256];
  int t = threadIdx.x;
  int own = (t < NBUCKET) ? bcnt[t] : 0;
  s[t] = own;
  __syncthreads();
  for (int o = 1; o < 256; o <<= 1) {
    int v = (t >= o) ? s[t - o] : 0;
    __syncthreads();
    s[t] += v;
    __syncthreads();
  }
  if (t < NBUCKET) {
    int excl = s[t] - own;
    bbase[t] = excl;
    bcursor[t] = excl;
  }
  if (t == 0) {
    bbase[NBUCKET] = N_EDGES;
    rowp[N_NODES] = N_EDGES;
  }
}

// entry = src | (dst & 511) << 17   (src < 2^17, dst_local < 512)
__global__ void partition_kernel(const int* __restrict__ src, const int* __restrict__ dst,
                                 int* __restrict__ bcursor, unsigned* __restrict__ ent) {
  __shared__ int cnt[256];
  __shared__ int cnt2[256];
  __shared__ int lstart[256];
  __shared__ int gbase[256];
  __shared__ int s[256];
  __shared__ unsigned sorted[TILE];
  __shared__ unsigned char bid[TILE];
  int t = threadIdx.x;
  int e0 = blockIdx.x * TILE;
  cnt[t] = 0; cnt2[t] = 0;
  __syncthreads();

  unsigned v[8];
  int b[8];
#pragma unroll
  for (int u = 0; u < 8; ++u) {
    int e = e0 + u * 256 + t;
    b[u] = -1;
    if (e < N_EDGES) {
      int d = dst[e];
      b[u] = d >> BSHIFT;
      v[u] = (unsigned)src[e] | ((unsigned)(d & 511) << 17);
      atomicAdd(&cnt[b[u]], 1);
    }
  }
  __syncthreads();
  s[t] = cnt[t];
  __syncthreads();
  for (int o = 1; o < 256; o <<= 1) {
    int x = (t >= o) ? s[t - o] : 0;
    __syncthreads();
    s[t] += x;
    __syncthreads();
  }
  lstart[t] = s[t] - cnt[t];
  __syncthreads();
  if (t < NBUCKET) gbase[t] = (cnt[t] > 0) ? atomicAdd(&bcursor[t], cnt[t]) : 0;
  __syncthreads();
#pragma unroll
  for (int u = 0; u < 8; ++u) {
    if (b[u] >= 0) {
      int p = lstart[b[u]] + atomicAdd(&cnt2[b[u]], 1);
      sorted[p] = v[u];
      bid[p] = (unsigned char)b[u];
    }
  }
  __syncthreads();
  int ntile = min(TILE, N_EDGES - e0);
  for (int i = t; i < ntile; i += 256) {
    int bb = bid[i];
    ent[gbase[bb] + (i - lstart[bb])] = sorted[i];
  }
}

__launch_bounds__(256)
__global__ void bucket_csr_kernel(const unsigned* __restrict__ ent,
                                  const int* __restrict__ bbase,
                                  int* __restrict__ rowp,
                                  int* __restrict__ ssrc) {
  __shared__ unsigned le[CSR_CAP];   // 32 KB
  __shared__ int deg[512];           // reused as scatter cursor
  __shared__ int excl[512];
  __shared__ int ws[256];
  int t = threadIdx.x;
  int b = blockIdx.x;
  int base = bbase[b];
  int cntb = bbase[b + 1] - base;
  deg[t] = 0; deg[t + 256] = 0;
  __syncthreads();
  for (int i = t; i < cntb; i += 256) {
    unsigned e = ent[base + i];
    if (i < CSR_CAP) le[i] = e;
    atomicAdd(&deg[e >> 17], 1);
  }
  __syncthreads();
  int d0 = deg[t * 2], d1 = deg[t * 2 + 1];
  int sum2 = d0 + d1;
  ws[t] = sum2;
  __syncthreads();
  for (int o = 1; o < 256; o <<= 1) {
    int x = (t >= o) ? ws[t - o] : 0;
    __syncthreads();
    ws[t] += x;
    __syncthreads();
  }
  int run = ws[t] - sum2;
  excl[t * 2] = run; run += d0;
  excl[t * 2 + 1] = run;
  __syncthreads();
  int node0 = b << BSHIFT;
#pragma unroll
  for (int k = 0; k < 2; ++k) {
    int i = t * 2 + k;
    int n = node0 + i;
    if (n < N_NODES) rowp[n] = base + excl[i];
    deg[i] = excl[i];
  }
  __syncthreads();
  for (int i = t; i < cntb; i += 256) {
    unsigned e = (i < CSR_CAP) ? le[i] : ent[base + i];
    int p = atomicAdd(&deg[e >> 17], 1);
    ssrc[base + p] = (int)(e & 0x1FFFFu);
  }
}

// ---------------- dense pipeline ---------------------------------------------
// h0 = x @ W_emb + b_emb   (x: [N,7], W: [7,64]) -> bf16
__global__ void embed_kernel(const float* __restrict__ x,
                             const float* __restrict__ W,
                             const float* __restrict__ b,
                             __bf16* __restrict__ h) {
  __shared__ float Ws[7 * 64];
  __shared__ float bs[64];
  int t = threadIdx.x;
  for (int i = t; i < 7 * 64; i += 256) Ws[i] = W[i];
  if (t < 64) bs[t] = b[t];
  __syncthreads();
  int gid = blockIdx.x * 256 + t;
  int n = gid >> 6, f = gid & 63;
  const float* xr = x + n * 7;
  float acc = bs[f];
#pragma unroll
  for (int k = 0; k < 7; ++k) acc = fmaf(xr[k], Ws[k * 64 + f], acc);
  h[gid] = (__bf16)acc;
}

// Pre-permute all 3 layers' weights into bf16 MFMA B-fragment order;
// also folds the pool-accumulator init.
__global__ void convert_all_kernel(const float* __restrict__ W1a, const float* __restrict__ W1b,
                                   const float* __restrict__ W2a, const float* __restrict__ W2b,
                                   const float* __restrict__ W3a, const float* __restrict__ W3b,
                                   __bf16* __restrict__ wp,
                                   float* gsum, unsigned* gmax, int* gcnt) {
  int o = blockIdx.x * 256 + threadIdx.x;  // 0..49151
  if (o < N_GRAPHS * 64) {
    gsum[o] = 0.0f;
    gmax[o] = 0x407FFFFFu;  // f2ord(-1.0f); elu outputs > -1, safe identity
  }
  if (o < N_GRAPHS) gcnt[o] = 0;
  int L = o >> 14, q = o & 16383;
  const float* Wa = (L == 0) ? W1a : (L == 1) ? W2a : W3a;
  const float* Wb = (L == 0) ? W1b : (L == 1) ? W2b : W3b;
  if (q < 8192) {
    int j = q & 7, c = (q >> 3) & 15, kc = (q >> 7) & 3, kt = (q >> 9) & 1, nt = q >> 10;
    wp[o] = (__bf16)Wa[(kt * 32 + kc * 8 + j) * 128 + nt * 16 + c];
  } else {
    int p = q - 8192;
    int j = p & 7, c = (p >> 3) & 15, kc = (p >> 7) & 3, kt = (p >> 9) & 3, nt2 = p >> 11;
    wp[o] = (__bf16)Wb[(kt * 32 + kc * 8 + j) * 64 + nt2 * 16 + c];
  }
}

// Shared MLP tail: GEMM1 -> relu -> GEMM2 -> elu -> hout (wave-private rows).
__device__ __forceinline__ void mlp_tail(const __bf16* AsW, __bf16* HsW,
                                         const __bf16* __restrict__ W1p,
                                         const float* __restrict__ b1,
                                         const __bf16* __restrict__ W2p,
                                         const float* __restrict__ b2,
                                         __bf16* __restrict__ hout,
                                         int n0b, int wv, int c, int kc, int m0) {
  bf16x8 a1_0 = *(const bf16x8*)&AsW[(m0 + c) * 72 + 0 * 32 + kc * 8];
  bf16x8 a1_1 = *(const bf16x8*)&AsW[(m0 + c) * 72 + 1 * 32 + kc * 8];
  f32x4 acc1[8];
#pragma unroll
  for (int nt = 0; nt < 8; ++nt) {
    float bv = b1[nt * 16 + c];
    f32x4 acc = {bv, bv, bv, bv};
    bf16x8 bf0 = *(const bf16x8*)&W1p[(nt * 2 + 0) * 512 + kc * 128 + c * 8];
    bf16x8 bf1 = *(const bf16x8*)&W1p[(nt * 2 + 1) * 512 + kc * 128 + c * 8];
    acc = __builtin_amdgcn_mfma_f32_16x16x32_bf16(a1_0, bf0, acc, 0, 0, 0);
    acc = __builtin_amdgcn_mfma_f32_16x16x32_bf16(a1_1, bf1, acc, 0, 0, 0);
    acc1[nt] = acc;
  }
#pragma unroll
  for (int nt = 0; nt < 8; ++nt) {
#pragma unroll
    for (int r = 0; r < 4; ++r) {
      HsW[(m0 + kc * 4 + r) * 136 + nt * 16 + c] = (__bf16)fmaxf(acc1[nt][r], 0.0f);
    }
  }
  bf16x8 a2[4];
#pragma unroll
  for (int kt = 0; kt < 4; ++kt)
    a2[kt] = *(const bf16x8*)&HsW[(m0 + c) * 136 + kt * 32 + kc * 8];
#pragma unroll
  for (int nt2 = 0; nt2 < 4; ++nt2) {
    float bv = b2[nt2 * 16 + c];
    f32x4 acc = {bv, bv, bv, bv};
#pragma unroll
    for (int kt = 0; kt < 4; ++kt) {
      bf16x8 bf = *(const bf16x8*)&W2p[(nt2 * 4 + kt) * 512 + kc * 128 + c * 8];
      acc = __builtin_amdgcn_mfma_f32_16x16x32_bf16(a2[kt], bf, acc, 0, 0, 0);
    }
#pragma unroll
    for (int r = 0; r < 4; ++r) {
      int g = n0b + m0 + kc * 4 + r;
      if (g < N_NODES) {
        float o = acc[r];
        hout[(size_t)g * 64 + nt2 * 16 + c] = (__bf16)((o > 0.0f) ? o : expm1f(o));
      }
    }
  }
}

// Quad-row CSR gather (rows rq,rq+4,rq+8,rq+12; 16 scalar-indexed loads in
// flight) + MFMA MLP. Wave-private rows, no __syncthreads. (r11-measured)
__launch_bounds__(256)
__global__ void gin_fused5_kernel(const __bf16* __restrict__ hin,
                                  __bf16* __restrict__ hout,
                                  const int* __restrict__ row_ptr,
                                  const int* __restrict__ ssrc,
                                  const float* __restrict__ eps_p,
                                  const __bf16* __restrict__ W1p,
                                  const float* __restrict__ b1,
                                  const __bf16* __restrict__ W2p,
                                  const float* __restrict__ b2) {
  __shared__ __bf16 As[64 * 72];
  __shared__ __bf16 Hs[64 * 136];
  int t = threadIdx.x, lane = t & 63, wv = t >> 6;
  int c = lane & 15, kc = lane >> 4;
  int m0 = wv * 16;
  float epsv = 1.0f + eps_p[0];
  int n0b = blockIdx.x * 64;
  int n0w = n0b + m0;

  int rp = row_ptr[min(n0w + min(lane, 16), N_NODES)];

#define DRAIN(j, e, acc) \
  while (j + 4 <= e) { \
    int q0 = ssrc[j], q1 = ssrc[j + 1], q2 = ssrc[j + 2], q3 = ssrc[j + 3]; \
    float g0 = (float)hin[(size_t)q0 * 64 + lane]; \
    float g1 = (float)hin[(size_t)q1 * 64 + lane]; \
    float g2 = (float)hin[(size_t)q2 * 64 + lane]; \
    float g3 = (float)hin[(size_t)q3 * 64 + lane]; \
    acc += (g0 + g1) + (g2 + g3); j += 4; \
  } \
  for (; j < e; ++j) acc += (float)hin[(size_t)ssrc[j] * 64 + lane];

  for (int rq = 0; rq < 4; ++rq) {
    int r0 = rq, r1 = rq + 4, r2 = rq + 8, r3 = rq + 12;
    int n0 = n0w + r0, n1 = n0w + r1, n2 = n0w + r2, n3 = n0w + r3;
    int j0 = __builtin_amdgcn_readfirstlane(__shfl(rp, r0));
    int e0 = __builtin_amdgcn_readfirstlane(__shfl(rp, r0 + 1));
    int j1 = __builtin_amdgcn_readfirstlane(__shfl(rp, r1));
    int e1 = __builtin_amdgcn_readfirstlane(__shfl(rp, r1 + 1));
    int j2 = __builtin_amdgcn_readfirstlane(__shfl(rp, r2));
    int e2 = __builtin_amdgcn_readfirstlane(__shfl(rp, r2 + 1));
    int j3 = __builtin_amdgcn_readfirstlane(__shfl(rp, r3));
    int e3 = __builtin_amdgcn_readfirstlane(__shfl(rp, r3 + 1));
    float a0 = (n0 < N_NODES) ? epsv * (float)hin[(size_t)n0 * 64 + lane] : 0.0f;
    float a1 = (n1 < N_NODES) ? epsv * (float)hin[(size_t)n1 * 64 + lane] : 0.0f;
    float a2 = (n2 < N_NODES) ? epsv * (float)hin[(size_t)n2 * 64 + lane] : 0.0f;
    float a3 = (n3 < N_NODES) ? epsv * (float)hin[(size_t)n3 * 64 + lane] : 0.0f;
    // joint phase: 16 loads in flight
    while (j0 + 4 <= e0 && j1 + 4 <= e1 && j2 + 4 <= e2 && j3 + 4 <= e3) {
      int s00 = ssrc[j0], s01 = ssrc[j0 + 1], s02 = ssrc[j0 + 2], s03 = ssrc[j0 + 3];
      int s10 = ssrc[j1], s11 = ssrc[j1 + 1], s12 = ssrc[j1 + 2], s13 = ssrc[j1 + 3];
      int s20 = ssrc[j2], s21 = ssrc[j2 + 1], s22 = ssrc[j2 + 2], s23 = ssrc[j2 + 3];
      int s30 = ssrc[j3], s31 = ssrc[j3 + 1], s32 = ssrc[j3 + 2], s33 = ssrc[j3 + 3];
      float f00 = (float)hin[(size_t)s00 * 64 + lane];
      float f01 = (float)hin[(size_t)s01 * 64 + lane];
      float f02 = (float)hin[(size_t)s02 * 64 + lane];
      float f03 = (float)hin[(size_t)s03 * 64 + lane];
      float f10 = (float)hin[(size_t)s10 * 64 + lane];
      float f11 = (float)hin[(size_t)s11 * 64 + lane];
      float f12 = (float)hin[(size_t)s12 * 64 + lane];
      float f13 = (float)hin[(size_t)s13 * 64 + lane];
      float f20 = (float)hin[(size_t)s20 * 64 + lane];
      float f21 = (float)hin[(size_t)s21 * 64 + lane];
      float f22 = (float)hin[(size_t)s22 * 64 + lane];
      float f23 = (float)hin[(size_t)s23 * 64 + lane];
      float f30 = (float)hin[(size_t)s30 * 64 + lane];
      float f31 = (float)hin[(size_t)s31 * 64 + lane];
      float f32_ = (float)hin[(size_t)s32 * 64 + lane];
      float f33 = (float)hin[(size_t)s33 * 64 + lane];
      a0 += (f00 + f01) + (f02 + f03);
      a1 += (f10 + f11) + (f12 + f13);
      a2 += (f20 + f21) + (f22 + f23);
      a3 += (f30 + f31) + (f32_ + f33);
      j0 += 4; j1 += 4; j2 += 4; j3 += 4;
    }
    DRAIN(j0, e0, a0);
    DRAIN(j1, e1, a1);
    DRAIN(j2, e2, a2);
    DRAIN(j3, e3, a3);
    As[(m0 + r0) * 72 + lane] = (__bf16)a0;
    As[(m0 + r1) * 72 + lane] = (__bf16)a1;
    As[(m0 + r2) * 72 + lane] = (__bf16)a2;
    As[(m0 + r3) * 72 + lane] = (__bf16)a3;
  }
#undef DRAIN

  mlp_tail(As, Hs, W1p, b1, W2p, b2, hout, n0b, wv, c, kc, m0);
}

// per-graph sum/max/count; batch sorted -> wave scans contiguous chunk.
// 4-row interleaved loads (4 in flight) to cut serial latency.
__global__ void pool_kernel(const __bf16* __restrict__ h,
                            const int* __restrict__ batch,
                            float* gsum, unsigned* gmax, int* gcnt) {
  int lane = threadIdx.x & 63;
  int wave = (blockIdx.x * blockDim.x + threadIdx.x) >> 6;
  int nwaves = (gridDim.x * blockDim.x) >> 6;
  int chunk = (N_NODES + nwaves - 1) / nwaves;
  int n0 = wave * chunk;
  int n1 = min(n0 + chunk, N_NODES);
  if (n0 >= N_NODES) return;
  int cur = batch[n0];
  float s = 0.0f, m = -2.0f;
  int cnt = 0;
#define POOL_ONE(g, v)                                         \
  if (g != cur) {                                              \
    atomicAdd(&gsum[cur * 64 + lane], s);                      \
    atomicMax(&gmax[cur * 64 + lane], f2ord(m));               \
    if (lane == 0) atomicAdd(&gcnt[cur], cnt);                 \
    cur = g; s = 0.0f; m = -2.0f; cnt = 0;                     \
  }                                                            \
  s += v; m = fmaxf(m, v); ++cnt;
  int n = n0;
  for (; n + 4 <= n1; n += 4) {
    int g0 = batch[n], g1 = batch[n + 1], g2 = batch[n + 2], g3 = batch[n + 3];
    float v0 = (float)h[(size_t)n * 64 + lane];
    float v1 = (float)h[(size_t)(n + 1) * 64 + lane];
    float v2 = (float)h[(size_t)(n + 2) * 64 + lane];
    float v3 = (float)h[(size_t)(n + 3) * 64 + lane];
    POOL_ONE(g0, v0);
    POOL_ONE(g1, v1);
    POOL_ONE(g2, v2);
    POOL_ONE(g3, v3);
  }
  for (; n < n1; ++n) {
    int g = batch[n];
    float v = (float)h[(size_t)n * 64 + lane];
    POOL_ONE(g, v);
  }
#undef POOL_ONE
  atomicAdd(&gsum[cur * 64 + lane], s);
  atomicMax(&gmax[cur * 64 + lane], f2ord(m));
  if (lane == 0) atomicAdd(&gcnt[cur], cnt);
}

// out = relu([mean|max] @ Wc1 + bc1) @ Wc2 + bc2 ; one 64-thread block / graph
__global__ void cls_kernel(const float* __restrict__ gsum,
                           const unsigned* __restrict__ gmax,
                           const int* __restrict__ gcnt,
                           const float* __restrict__ Wc1,
                           const float* __restrict__ bc1,
                           const float* __restrict__ Wc2,
                           const float* __restrict__ bc2,
                           float* __restrict__ out) {
  __shared__ float gv[128];
  __shared__ float tv[64];
  int g = blockIdx.x, l = threadIdx.x;
  float cnt = fmaxf((float)gcnt[g], 1.0f);
  gv[l] = gsum[g * 64 + l] / cnt;
  gv[64 + l] = ord2f(gmax[g * 64 + l]);
  __syncthreads();
  float acc = bc1[l];
#pragma unroll 8
  for (int k = 0; k < 128; ++k) acc = fmaf(gv[k], Wc1[k * 64 + l], acc);
  tv[l] = fmaxf(acc, 0.0f);
  __syncthreads();
  if (l < 10) {
    float o = bc2[l];
#pragma unroll
    for (int k = 0; k < 64; ++k) o = fmaf(tv[k], Wc2[k * 10 + l], o);
    out[g * 10 + l] = o;
  }
}

extern "C" void kernel_launch(void* const* d_in, const int* in_sizes, int n_in,
                              void* d_out, int out_size, void* d_ws, size_t ws_size,
                              hipStream_t stream) {
  const float* x     = (const float*)d_in[0];
  const int*   ei    = (const int*)d_in[1];
  const int*   batch = (const int*)d_in[2];
  const float* W_emb = (const float*)d_in[3];
  const float* b_emb = (const float*)d_in[4];
  const float* eps1  = (const float*)d_in[5];
  const float* W1a   = (const float*)d_in[6];
  const float* b1a   = (const float*)d_in[7];
  const float* W1b   = (const float*)d_in[8];
  const float* b1b   = (const float*)d_in[9];
  const float* eps2  = (const float*)d_in[10];
  const float* W2a   = (const float*)d_in[11];
  const float* b2a   = (const float*)d_in[12];
  const float* W2b   = (const float*)d_in[13];
  const float* b2b   = (const float*)d_in[14];
  const float* eps3  = (const float*)d_in[15];
  const float* W3a   = (const float*)d_in[16];
  const float* b3a   = (const float*)d_in[17];
  const float* W3b   = (const float*)d_in[18];
  const float* b3b   = (const float*)d_in[19];
  const float* Wc1   = (const float*)d_in[20];
  const float* bc1   = (const float*)d_in[21];
  const float* Wc2   = (const float*)d_in[22];
  const float* bc2   = (const float*)d_in[23];
  float* out = (float*)d_out;

  // workspace layout (byte-based)
  char* w = (char*)d_ws;
  __bf16*   h0   = (__bf16*)w;                     w += (size_t)N_NODES * 64 * 2;  // 12.8MB
  __bf16*   h1   = (__bf16*)w;                     w += (size_t)N_NODES * 64 * 2;  // 12.8MB
  float*    gsum = (float*)w;                      w += N_GRAPHS * 64 * 4;
  unsigned* gmax = (unsigned*)w;                   w += N_GRAPHS * 64 * 4;
  int*      gcnt = (int*)w;                        w += N_GRAPHS * 4;
  __bf16*   wp   = (__bf16*)w;                     w += 3 * 16384 * 2;
  int*      bcnt = (int*)w;                        w += 256 * 4;
  int*      bbase= (int*)w;                        w += 260 * 4;
  int*      bcur = (int*)w;                        w += 256 * 4;
  int*      rowp = (int*)w;                        w += (size_t)(N_NODES + 1) * 4;
  unsigned* ent  = (unsigned*)w;                   w += (size_t)N_EDGES * 4;      // 4.8MB
  int*      ssrc = (int*)w;                        w += (size_t)N_EDGES * 4;      // 4.8MB

  const int* src = ei;             // edge_index[0]
  const int* dst = ei + N_EDGES;   // edge_index[1]

  const float* epss[3] = {eps1, eps2, eps3};
  const float* bas[3]  = {b1a, b2a, b3a};
  const float* bbs[3]  = {b1b, b2b, b3b};

  // ---- CSR build via two-level counting sort (edge list shared by layers) --
  hipMemsetAsync(bcnt, 0, 256 * sizeof(int), stream);
  bucket_hist_kernel<<<256, 256, 0, stream>>>(dst, bcnt);
  bucket_scan_kernel<<<1, 256, 0, stream>>>(bcnt, bbase, bcur, rowp);
  partition_kernel<<<(N_EDGES + TILE - 1) / TILE, 256, 0, stream>>>(src, dst, bcur, ent);
  bucket_csr_kernel<<<NBUCKET, 256, 0, stream>>>(ent, bbase, rowp, ssrc);

  convert_all_kernel<<<192, 256, 0, stream>>>(W1a, W1b, W2a, W2b, W3a, W3b, wp,
                                              gsum, gmax, gcnt);
  embed_kernel<<<(N_NODES * 64) / 256, 256, 0, stream>>>(x, W_emb, b_emb, h0);

  const int NGB = (N_NODES + 63) / 64;
  __bf16* hbuf[4] = {h0, h1, h0, h1};
  for (int L = 0; L < 3; ++L) {
    gin_fused5_kernel<<<NGB, 256, 0, stream>>>(
        hbuf[L], hbuf[L + 1], rowp, ssrc, epss[L],
        wp + (size_t)L * 16384, bas[L],
        wp + (size_t)L * 16384 + 8192, bbs[L]);
  }

  pool_kernel<<<512, 256, 0, stream>>>(h1, batch, gsum, gmax, gcnt);
  cls_kernel<<<N_GRAPHS, 64, 0, stream>>>(gsum, gmax, gcnt, Wc1, bc1, Wc2, bc2, out);
}